// Round 2
// baseline (852.242 us; speedup 1.0000x reference)
//
#include <hip/hip_runtime.h>

typedef __bf16 bfx8 __attribute__((ext_vector_type(8)));
typedef __bf16 bfx4 __attribute__((ext_vector_type(4)));
typedef float  f32x4 __attribute__((ext_vector_type(4)));

#define MFMA16(a,b,c) __builtin_amdgcn_mfma_f32_16x16x32_bf16((a),(b),(c),0,0,0)

static constexpr int BATCH = 8;
static constexpr int NTOK  = 4096;   // 64*64 spatial
static constexpr int CH    = 512;
static constexpr float GN_EPS = 1e-5f;
static constexpr float ATT_SCALE = 0.044194173824159216f; // 512^-0.5

// direct HBM->LDS, 16B per lane; LDS dest = wave-uniform base + lane*16
__device__ __forceinline__ void gload16(const void* g, void* l)
{
    __builtin_amdgcn_global_load_lds(
        (const __attribute__((address_space(1))) unsigned int*)g,
        (__attribute__((address_space(3))) unsigned int*)l, 16, 0, 0);
}

// ---------------------------------------------------------------------------
// prep: fp32 weights -> bf16 transposed (wT[n][c] = w[c][n]); concat fp32 biases.
// grid (16,16,4) z: 0=wq 1=wk 2=wv 3=wo. block 256.
// ---------------------------------------------------------------------------
__global__ __launch_bounds__(256)
void prep_weights(const float* __restrict__ wq, const float* __restrict__ wk,
                  const float* __restrict__ wv, const float* __restrict__ wo,
                  const float* __restrict__ bq, const float* __restrict__ bk,
                  const float* __restrict__ bv,
                  __bf16* __restrict__ wqkvT, __bf16* __restrict__ woT,
                  float* __restrict__ bqkv)
{
    __shared__ __bf16 t[32][36];
    const int z  = blockIdx.z;
    const float* src = (z == 0) ? wq : (z == 1) ? wk : (z == 2) ? wv : wo;
    const int c0 = blockIdx.x * 32, n0 = blockIdx.y * 32;
    const int tid = threadIdx.x;
    const int r = tid >> 3, c4 = (tid & 7) * 4;

    f32x4 in = *(const f32x4*)&src[(size_t)(c0 + r) * 512 + n0 + c4];
    bfx4 tv;
#pragma unroll
    for (int i = 0; i < 4; ++i) tv[i] = (__bf16)in[i];
    *(bfx4*)&t[r][c4] = tv;
    __syncthreads();
    bfx4 o;
#pragma unroll
    for (int i = 0; i < 4; ++i) o[i] = t[c4 + i][r];
    if (z < 3)
        *(bfx4*)&wqkvT[((size_t)(z * 512 + n0 + r)) * 512 + c0 + c4] = o;
    else
        *(bfx4*)&woT[((size_t)(n0 + r)) * 512 + c0 + c4] = o;

    if (z < 3 && blockIdx.x == 0 && blockIdx.y == 0) {
        const float* bs = (z == 0) ? bq : (z == 1) ? bk : bv;
        bqkv[z * 512 + tid]       = bs[tid];
        bqkv[z * 512 + tid + 256] = bs[tid + 256];
    }
}

// ---------------------------------------------------------------------------
// GroupNorm statistics: one block per (g, b). Writes per-channel fused
// scale/bias:  h[ch] = x[ch]*scA[b][ch] + biA[b][ch].  grid (32, 8), block 256.
// ---------------------------------------------------------------------------
__global__ __launch_bounds__(256)
void gn_stats(const float* __restrict__ x, const float* __restrict__ gs,
              const float* __restrict__ gb,
              float* __restrict__ scA, float* __restrict__ biA)
{
    const int g = blockIdx.x, b = blockIdx.y;
    const int tid = threadIdx.x;
    const int half = tid & 1;
    const size_t base = (size_t)b * NTOK * CH + g * 16 + half * 8;

    float sum = 0.f, sumsq = 0.f;
    for (int i = tid; i < 2 * NTOK; i += 256) {
        const int s = i >> 1;
        f32x4 v0 = *(const f32x4*)&x[base + (size_t)s * CH];
        f32x4 v1 = *(const f32x4*)&x[base + (size_t)s * CH + 4];
#pragma unroll
        for (int j = 0; j < 4; ++j) {
            sum += v0[j] + v1[j];
            sumsq += v0[j] * v0[j] + v1[j] * v1[j];
        }
    }
#pragma unroll
    for (int o = 32; o; o >>= 1) { sum += __shfl_down(sum, o); sumsq += __shfl_down(sumsq, o); }
    __shared__ float red[8];
    __shared__ float stats[2];
    const int w = tid >> 6;
    if ((tid & 63) == 0) { red[w] = sum; red[4 + w] = sumsq; }
    __syncthreads();
    if (tid == 0) {
        float s1 = red[0] + red[1] + red[2] + red[3];
        float s2 = red[4] + red[5] + red[6] + red[7];
        float mean = s1 * (1.f / 65536.f);
        float var  = s2 * (1.f / 65536.f) - mean * mean;
        stats[0] = mean; stats[1] = rsqrtf(var + GN_EPS);
    }
    __syncthreads();
    if (tid < 16) {
        const int ch = g * 16 + tid;
        const float sc = gs[ch] * stats[1];
        scA[b * 512 + ch] = sc;
        biA[b * 512 + ch] = gb[ch] - stats[0] * sc;
    }
}

// ---------------------------------------------------------------------------
// Fused GN-normalize + QKV GEMM.  A = x*sc+bi (fp32->bf16), B = wqkvT rows.
//   n in [0,1024): qk[m][n] = C + bias
//   n in [1024,1536): C+bias -> transposed into vT[b][ch][tok] via LDS
// 128x128 tile, BK=32, 4 waves. grid (M/128, 12), block 256.
// ---------------------------------------------------------------------------
__global__ __launch_bounds__(256)
void gemm_qkv(const float* __restrict__ x, const float* __restrict__ scA,
              const float* __restrict__ biA, const __bf16* __restrict__ Bt,
              const float* __restrict__ bias,
              __bf16* __restrict__ qk, __bf16* __restrict__ vT)
{
    const int bm = blockIdx.x * 128, bn = blockIdx.y * 128;
    const int tid = threadIdx.x;
    const int w = tid >> 6, lane = tid & 63, quad = lane >> 4, l15 = lane & 15;
    const int wm = (w >> 1) * 64, wn = (w & 1) * 64;
    const int brow = bm >> 12;                  // batch of this m-tile

    __shared__ __bf16 sAB[2][128][40];          // As = sAB[0], Bs = sAB[1]

    f32x4 acc[4][4];
#pragma unroll
    for (int i = 0; i < 4; ++i)
#pragma unroll
        for (int j = 0; j < 4; ++j) acc[i][j] = (f32x4){0.f, 0.f, 0.f, 0.f};

    const int sr = tid >> 2, scol = (tid & 3) * 8;
    for (int k0 = 0; k0 < 512; k0 += 32) {
        __syncthreads();
        {   // A: load fp32 x, apply GN scale/bias, stage bf16
            const float* scp = scA + brow * 512 + k0 + scol;
            const float* bip = biA + brow * 512 + k0 + scol;
            f32x4 s0v = *(const f32x4*)&scp[0], s1v = *(const f32x4*)&scp[4];
            f32x4 b0v = *(const f32x4*)&bip[0], b1v = *(const f32x4*)&bip[4];
            f32x4 xa0 = *(const f32x4*)&x[(size_t)(bm + sr) * 512 + k0 + scol];
            f32x4 xa1 = *(const f32x4*)&x[(size_t)(bm + sr) * 512 + k0 + scol + 4];
            f32x4 xb0 = *(const f32x4*)&x[(size_t)(bm + sr + 64) * 512 + k0 + scol];
            f32x4 xb1 = *(const f32x4*)&x[(size_t)(bm + sr + 64) * 512 + k0 + scol + 4];
            bfx8 ha, hb;
#pragma unroll
            for (int j = 0; j < 4; ++j) {
                ha[j]     = (__bf16)(xa0[j] * s0v[j] + b0v[j]);
                ha[4 + j] = (__bf16)(xa1[j] * s1v[j] + b1v[j]);
                hb[j]     = (__bf16)(xb0[j] * s0v[j] + b0v[j]);
                hb[4 + j] = (__bf16)(xb1[j] * s1v[j] + b1v[j]);
            }
            *(bfx8*)&sAB[0][sr][scol]      = ha;
            *(bfx8*)&sAB[0][sr + 64][scol] = hb;
        }
        *(bfx8*)&sAB[1][sr][scol]      = *(const bfx8*)&Bt[(size_t)(bn + sr) * 512 + k0 + scol];
        *(bfx8*)&sAB[1][sr + 64][scol] = *(const bfx8*)&Bt[(size_t)(bn + sr + 64) * 512 + k0 + scol];
        __syncthreads();
        bfx8 af[4], bfr[4];
#pragma unroll
        for (int mi = 0; mi < 4; ++mi) af[mi]  = *(const bfx8*)&sAB[0][wm + mi * 16 + l15][quad * 8];
#pragma unroll
        for (int ni = 0; ni < 4; ++ni) bfr[ni] = *(const bfx8*)&sAB[1][wn + ni * 16 + l15][quad * 8];
#pragma unroll
        for (int mi = 0; mi < 4; ++mi)
#pragma unroll
            for (int ni = 0; ni < 4; ++ni)
                acc[mi][ni] = MFMA16(af[mi], bfr[ni], acc[mi][ni]);
    }

    if (blockIdx.y < 8) {
        // q/k epilogue: direct store, D row = quad*4+reg, col = l15
#pragma unroll
        for (int ni = 0; ni < 4; ++ni) {
            const int col = bn + wn + ni * 16 + l15;
            const float bv = bias[col];
#pragma unroll
            for (int mi = 0; mi < 4; ++mi)
#pragma unroll
                for (int rr = 0; rr < 4; ++rr) {
                    const int row = bm + wm + mi * 16 + quad * 4 + rr;
                    qk[(size_t)row * 1024 + col] = (__bf16)(acc[mi][ni][rr] + bv);
                }
        }
    } else {
        // v epilogue: transpose 128x128 tile into vT[b][ch][tok] via LDS
        const int vch0 = bn - 1024;
        const int tokbase = bm & 4095;
        __bf16* tb = &sAB[0][0][0];             // reuse As+Bs: [64][136] bf16
        __syncthreads();                         // all waves done reading frags
#pragma unroll
        for (int chunk = 0; chunk < 2; ++chunk) {
            if ((w & 1) == chunk) {
#pragma unroll
                for (int ni = 0; ni < 4; ++ni) {
                    const int chc = ni * 16 + l15;               // 0..63 in chunk
                    const float bv = bias[bn + chunk * 64 + chc];
#pragma unroll
                    for (int mi = 0; mi < 4; ++mi)
#pragma unroll
                        for (int rr = 0; rr < 4; ++rr) {
                            const int tok = wm + mi * 16 + quad * 4 + rr;
                            tb[chc * 136 + tok] = (__bf16)(acc[mi][ni][rr] + bv);
                        }
                }
            }
            __syncthreads();
            {   // cooperative coalesced store of the 64ch x 128tok chunk
                const int chn = tid >> 2, t0 = (tid & 3) * 32;
                const size_t gb0 =
                    ((size_t)(brow * 512 + vch0 + chunk * 64 + chn)) * 4096 + tokbase;
#pragma unroll
                for (int u = 0; u < 4; ++u)
                    *(bfx8*)&vT[gb0 + t0 + u * 8] = *(const bfx8*)&tb[chn * 136 + t0 + u * 8];
            }
            __syncthreads();
        }
    }
}

// ---------------------------------------------------------------------------
// Flash attention + fused output projection + residual (fp32 out), v5.
// v4's single-barrier DMA pipeline + CHANNEL-SPLIT PV (LDS-volume cut):
//   v4 read 64KB LDS per wave per iter (full K + full V) because PV was
//   wave-local.  v5 shares P through LDS so wave w's PV covers channels
//   [w*64, w*64+64) x ALL 128 q: V reads drop 32KB -> 4KB/wave, P reads 8KB.
//   Per-CU per-iter LDS reads: 512KB -> ~352KB (the LDS port was the
//   measured bottleneck: ~55% of iter time at MfmaUtil 22%).
// Sync: barrier A = __syncthreads (vmcnt-draining; the DMA pipeline sync,
//   one per iter).  Barrier B = raw "s_waitcnt lgkmcnt(0); s_barrier" for
//   P/abuf visibility -- does NOT drain vmcnt, so the K/V DMA issued after
//   A stays in flight across it.
// QK/softmax unchanged (wave-local, 16 q-rows per wave, S^T via mfma(K,Q)).
// Rescale alpha + final 1/l via abuf/lbuf (+rflag skip), read post-B.
// oacc: O^T[ch=w*64+ct*16+quad*4+r][q=qt*16+l15], 4x8 f32x4 = 128 regs.
// grid (NTOK/128, B), block 512 (8 waves).
// ---------------------------------------------------------------------------
__global__ __launch_bounds__(512, 2)
void attn_fused(const __bf16* __restrict__ qk, const __bf16* __restrict__ vT,
                const __bf16* __restrict__ woT, const float* __restrict__ bo,
                const float* __restrict__ x, float* __restrict__ out)
{
    const int bb = blockIdx.y;
    const int q0 = blockIdx.x * 128;
    const int tid = threadIdx.x;
    const int w = tid >> 6, lane = tid & 63, quad = lane >> 4, l15 = lane & 15;

    __shared__ __attribute__((aligned(16))) unsigned char smem[142352];
    __bf16 (*Ks)[32][512]      = (__bf16(*)[32][512])smem;                // 2 x 32 KiB
    __bf16 (*Vs)[32][4][16][8] = (__bf16(*)[32][4][16][8])(smem + 65536); // 2 x 32 KiB
    __bf16 (*Ph)[40]           = (__bf16(*)[40])(smem + 131072);          // 128x40 (10240 B)
    float* abuf  = (float*)(smem + 141312);                               // 128 f32
    float* lbuf  = (float*)(smem + 141824);                               // 128 f32
    int*   rflag = (int*)(smem + 142336);                                 // 2 ints
    __bf16 (*Obuf)[520] = (__bf16(*)[520])smem;                           // 64x520 epilogue overlay

    // Q rows for this wave's S^T columns, full K=512, in registers (64 VGPRs)
    bfx8 qf[16];
    {
        const __bf16* qptr = qk + ((size_t)(bb * NTOK + q0 + w * 16 + l15)) * 1024;
#pragma unroll
        for (int kk = 0; kk < 16; ++kk)
            qf[kk] = *(const bfx8*)&qptr[kk * 32 + quad * 8];
    }

    // O^T accumulator: wave w owns channels [w*64, w*64+64) for ALL 128 q.
    // oacc[ct][qt]: ch = w*64 + ct*16 + quad*4 + r, q = qt*16 + l15.  128 regs.
    f32x4 oacc[4][8];
#pragma unroll
    for (int i = 0; i < 4; ++i)
#pragma unroll
        for (int j = 0; j < 8; ++j) oacc[i][j] = (f32x4){0.f, 0.f, 0.f, 0.f};
    float mcur = -1e30f, lcur = 0.f;

    // ---- tile-0 DMA: wave w stages K rows [w*4,w*4+4) and V ch-groups [w*4,w*4+4)
#pragma unroll
    for (int u = 0; u < 4; ++u) {
        const int r = w * 4 + u;
        gload16(qk + ((size_t)(bb * NTOK + r)) * 1024 + 512 + ((lane ^ (r & 7)) * 8),
                &Ks[0][r][0]);
    }
#pragma unroll
    for (int u = 0; u < 4; ++u) {
        const int g = w * 4 + u;
        gload16(vT + ((size_t)(bb * 512 + g * 16 + (lane & 15))) * 4096 + (lane >> 4) * 8,
                &Vs[0][g][0][0][0]);
    }

    const int NT = NTOK / 32;   // 128
    int buf = 0;
    for (int kt = 0; kt < NT; ++kt) {
        // barrier A: tile kt's DMA drained (vmcnt 0), buf^1 free to overwrite.
        __syncthreads();

        if (kt + 1 < NT) {
            const int kv1 = (kt + 1) * 32;
            const int nb = buf ^ 1;
#pragma unroll
            for (int u = 0; u < 4; ++u) {
                const int r = w * 4 + u;
                gload16(qk + ((size_t)(bb * NTOK + kv1 + r)) * 1024 + 512 + ((lane ^ (r & 7)) * 8),
                        &Ks[nb][r][0]);
            }
#pragma unroll
            for (int u = 0; u < 4; ++u) {
                const int g = w * 4 + u;
                gload16(vT + ((size_t)(bb * 512 + g * 16 + (lane & 15))) * 4096 + kv1 + (lane >> 4) * 8,
                        &Vs[nb][g][0][0][0]);
            }
        }

        // S^T: s0 -> j = quad*4+i, s1 -> j = 16+quad*4+i, column m = l15.
        // K read swizzled: phys chunk = (kk*4+quad) ^ (l15&7)
        f32x4 s0 = (f32x4){0.f, 0.f, 0.f, 0.f}, s1 = (f32x4){0.f, 0.f, 0.f, 0.f};
#pragma unroll
        for (int kk = 0; kk < 16; ++kk) {
            const int pc = (((kk * 4 + quad) ^ (l15 & 7)) * 8);
            bfx8 kb0 = *(const bfx8*)&Ks[buf][l15][pc];
            bfx8 kb1 = *(const bfx8*)&Ks[buf][16 + l15][pc];
            s0 = MFMA16(kb0, qf[kk], s0);
            s1 = MFMA16(kb1, qf[kk], s1);
        }

        // wave-local online softmax for row m = l15 (replicated across quads)
        float mx = -1e30f;
#pragma unroll
        for (int i = 0; i < 4; ++i) {
            s0[i] *= ATT_SCALE; s1[i] *= ATT_SCALE;
            mx = fmaxf(mx, fmaxf(s0[i], s1[i]));
        }
        mx = fmaxf(mx, __shfl_xor(mx, 16));
        mx = fmaxf(mx, __shfl_xor(mx, 32));
        const float mnew = fmaxf(mcur, mx);
        const float al = __expf(mcur - mnew);
        float ps = 0.f;
        bfx4 pl0, pl1;
#pragma unroll
        for (int i = 0; i < 4; ++i) { float p = __expf(s0[i] - mnew); ps += p; pl0[i] = (__bf16)p; }
#pragma unroll
        for (int i = 0; i < 4; ++i) { float p = __expf(s1[i] - mnew); ps += p; pl1[i] = (__bf16)p; }
        ps += __shfl_xor(ps, 16);
        ps += __shfl_xor(ps, 32);
        lcur = lcur * al + ps;
        mcur = mnew;

        // publish P row (q = w*16+l15) and alpha; set block rescale flag
        *(bfx4*)&Ph[w * 16 + l15][quad * 4]      = pl0;
        *(bfx4*)&Ph[w * 16 + l15][16 + quad * 4] = pl1;
        if (quad == 0) abuf[w * 16 + l15] = al;
        if (__ballot(al != 1.0f)) { if (lane == 0) rflag[kt & 1] = 1; }
        if (tid == 0) rflag[(kt + 1) & 1] = 0;

        // barrier B: P/abuf/rflag visible block-wide; vmcnt NOT drained,
        // so the tile kt+1 DMA stays in flight.
        asm volatile("s_waitcnt lgkmcnt(0)\n\ts_barrier" ::: "memory");

        // conditional O rescale: lane's cols are q = qt*16+l15
        if (rflag[kt & 1]) {
#pragma unroll
            for (int qt = 0; qt < 8; ++qt) {
                const float a = abuf[qt * 16 + l15];
#pragma unroll
                for (int ct = 0; ct < 4; ++ct)
#pragma unroll
                    for (int r = 0; r < 4; ++r) oacc[ct][qt][r] *= a;
            }
        }

        // PV: O^T[w's 64 ch][all 128 q] += V-slice * P
        bfx8 vb[4];
#pragma unroll
        for (int ct = 0; ct < 4; ++ct)
            vb[ct] = *(const bfx8*)&Vs[buf][w * 4 + ct][quad][l15][0];
#pragma unroll
        for (int qt = 0; qt < 8; ++qt) {
            bfx8 pa = *(const bfx8*)&Ph[qt * 16 + l15][quad * 8];
#pragma unroll
            for (int ct = 0; ct < 4; ++ct)
                oacc[ct][qt] = MFMA16(vb[ct], pa, oacc[ct][qt]);
        }
        buf ^= 1;
    }

    // ---- epilogue: normalize + projection + bias + residual, 2 half-passes --
    if (quad == 0) lbuf[w * 16 + l15] = lcur;

#pragma unroll
    for (int h = 0; h < 2; ++h) {
        __syncthreads();   // lbuf visible + K/V loop reads done (h=0) / prev half read (h=1)
        // write Obuf rows q in [h*64, h*64+64): each wave contributes its 64 ch
#pragma unroll
        for (int t = 0; t < 4; ++t) {
            const int qt = h * 4 + t;
            const float linv = 1.f / lbuf[qt * 16 + l15];
#pragma unroll
            for (int ct = 0; ct < 4; ++ct) {
                bfx4 ov;
#pragma unroll
                for (int r = 0; r < 4; ++r) ov[r] = (__bf16)(oacc[ct][qt][r] * linv);
                *(bfx4*)&Obuf[t * 16 + l15][w * 64 + ct * 16 + quad * 4] = ov;
            }
        }
        __syncthreads();

        // project rows [h*64, h*64+64): wave strip rows (w&3)*16, cols (w>>2)*256
        const int rs  = (w & 3) * 16;
        const int nt0 = (w >> 2) * 16;
        bfx8 af2[16];
#pragma unroll
        for (int k0 = 0; k0 < 16; ++k0)
            af2[k0] = *(const bfx8*)&Obuf[rs + l15][k0 * 32 + quad * 8];
#pragma unroll 4
        for (int nt = 0; nt < 16; ++nt) {
            f32x4 a2 = (f32x4){0.f, 0.f, 0.f, 0.f};
#pragma unroll
            for (int k0 = 0; k0 < 16; ++k0) {
                bfx8 wb = *(const bfx8*)&woT[(size_t)((nt0 + nt) * 16 + l15) * 512 + k0 * 32 + quad * 8];
                a2 = MFMA16(af2[k0], wb, a2);
            }
            const int col = (nt0 + nt) * 16 + l15;
            const float bv = bo[col];
#pragma unroll
            for (int rr = 0; rr < 4; ++rr) {
                const size_t idx =
                    ((size_t)(bb * NTOK + q0 + h * 64 + rs + quad * 4 + rr)) * 512 + col;
                out[idx] = a2[rr] + bv + x[idx];
            }
        }
    }
}

// ---------------------------------------------------------------------------
extern "C" void kernel_launch(void* const* d_in, const int* in_sizes, int n_in,
                              void* d_out, int out_size, void* d_ws, size_t ws_size,
                              hipStream_t stream)
{
    const float* x  = (const float*)d_in[0];
    const float* gs = (const float*)d_in[1];
    const float* gb = (const float*)d_in[2];
    const float* wq = (const float*)d_in[3];
    const float* bq = (const float*)d_in[4];
    const float* wk = (const float*)d_in[5];
    const float* bk = (const float*)d_in[6];
    const float* wv = (const float*)d_in[7];
    const float* bv = (const float*)d_in[8];
    const float* wo = (const float*)d_in[9];
    const float* bo = (const float*)d_in[10];
    float* out = (float*)d_out;

    // workspace layout -- total 102,799,360 B (~98 MiB)
    char* ws = (char*)d_ws;
    __bf16* qk    = (__bf16*)(ws);                    //  67,108,864 B [32768][1024]
    __bf16* vT    = (__bf16*)(ws + 67108864);         //  33,554,432 B [8][512][4096]
    __bf16* wqkvT = (__bf16*)(ws + 100663296);        //   1,572,864 B [1536][512]
    __bf16* woT   = (__bf16*)(ws + 102236160);        //     524,288 B [512][512]
    float*  bqkv  = (float* )(ws + 102760448);        //       6,144 B [1536]
    float*  scA   = (float* )(ws + 102766592);        //      16,384 B [8][512]
    float*  biA   = (float* )(ws + 102782976);        //      16,384 B [8][512]

    prep_weights<<<dim3(16, 16, 4), 256, 0, stream>>>(wq, wk, wv, wo, bq, bk, bv,
                                                      wqkvT, woT, bqkv);
    gn_stats<<<dim3(32, BATCH), 256, 0, stream>>>(x, gs, gb, scA, biA);
    gemm_qkv<<<dim3(256, 12), 256, 0, stream>>>(x, scA, biA, wqkvT, bqkv, qk, vT);
    attn_fused<<<dim3(NTOK / 128, BATCH), 512, 0, stream>>>(qk, vT, woT, bo, x, out);
}

// Round 3
// 739.921 us; speedup vs baseline: 1.1518x; 1.1518x over previous
//
#include <hip/hip_runtime.h>

typedef __bf16 bfx8 __attribute__((ext_vector_type(8)));
typedef __bf16 bfx4 __attribute__((ext_vector_type(4)));
typedef float  f32x4 __attribute__((ext_vector_type(4)));

#define MFMA16(a,b,c) __builtin_amdgcn_mfma_f32_16x16x32_bf16((a),(b),(c),0,0,0)

static constexpr int BATCH = 8;
static constexpr int NTOK  = 4096;   // 64*64 spatial
static constexpr int CH    = 512;
static constexpr float GN_EPS = 1e-5f;
static constexpr float ATT_SCALE = 0.044194173824159216f; // 512^-0.5

// direct HBM->LDS, 16B per lane; LDS dest = wave-uniform base + lane*16
__device__ __forceinline__ void gload16(const void* g, void* l)
{
    __builtin_amdgcn_global_load_lds(
        (const __attribute__((address_space(1))) unsigned int*)g,
        (__attribute__((address_space(3))) unsigned int*)l, 16, 0, 0);
}

// ---------------------------------------------------------------------------
// prep: fp32 weights -> bf16 transposed (wT[n][c] = w[c][n]); concat fp32 biases.
// grid (16,16,4) z: 0=wq 1=wk 2=wv 3=wo. block 256.
// ---------------------------------------------------------------------------
__global__ __launch_bounds__(256)
void prep_weights(const float* __restrict__ wq, const float* __restrict__ wk,
                  const float* __restrict__ wv, const float* __restrict__ wo,
                  const float* __restrict__ bq, const float* __restrict__ bk,
                  const float* __restrict__ bv,
                  __bf16* __restrict__ wqkvT, __bf16* __restrict__ woT,
                  float* __restrict__ bqkv)
{
    __shared__ __bf16 t[32][36];
    const int z  = blockIdx.z;
    const float* src = (z == 0) ? wq : (z == 1) ? wk : (z == 2) ? wv : wo;
    const int c0 = blockIdx.x * 32, n0 = blockIdx.y * 32;
    const int tid = threadIdx.x;
    const int r = tid >> 3, c4 = (tid & 7) * 4;

    f32x4 in = *(const f32x4*)&src[(size_t)(c0 + r) * 512 + n0 + c4];
    bfx4 tv;
#pragma unroll
    for (int i = 0; i < 4; ++i) tv[i] = (__bf16)in[i];
    *(bfx4*)&t[r][c4] = tv;
    __syncthreads();
    bfx4 o;
#pragma unroll
    for (int i = 0; i < 4; ++i) o[i] = t[c4 + i][r];
    if (z < 3)
        *(bfx4*)&wqkvT[((size_t)(z * 512 + n0 + r)) * 512 + c0 + c4] = o;
    else
        *(bfx4*)&woT[((size_t)(n0 + r)) * 512 + c0 + c4] = o;

    if (z < 3 && blockIdx.x == 0 && blockIdx.y == 0) {
        const float* bs = (z == 0) ? bq : (z == 1) ? bk : bv;
        bqkv[z * 512 + tid]       = bs[tid];
        bqkv[z * 512 + tid + 256] = bs[tid + 256];
    }
}

// ---------------------------------------------------------------------------
// GroupNorm statistics: one block per (g, b). Writes per-channel fused
// scale/bias:  h[ch] = x[ch]*scA[b][ch] + biA[b][ch].  grid (32, 8), block 256.
// ---------------------------------------------------------------------------
__global__ __launch_bounds__(256)
void gn_stats(const float* __restrict__ x, const float* __restrict__ gs,
              const float* __restrict__ gb,
              float* __restrict__ scA, float* __restrict__ biA)
{
    const int g = blockIdx.x, b = blockIdx.y;
    const int tid = threadIdx.x;
    const int half = tid & 1;
    const size_t base = (size_t)b * NTOK * CH + g * 16 + half * 8;

    float sum = 0.f, sumsq = 0.f;
    for (int i = tid; i < 2 * NTOK; i += 256) {
        const int s = i >> 1;
        f32x4 v0 = *(const f32x4*)&x[base + (size_t)s * CH];
        f32x4 v1 = *(const f32x4*)&x[base + (size_t)s * CH + 4];
#pragma unroll
        for (int j = 0; j < 4; ++j) {
            sum += v0[j] + v1[j];
            sumsq += v0[j] * v0[j] + v1[j] * v1[j];
        }
    }
#pragma unroll
    for (int o = 32; o; o >>= 1) { sum += __shfl_down(sum, o); sumsq += __shfl_down(sumsq, o); }
    __shared__ float red[8];
    __shared__ float stats[2];
    const int w = tid >> 6;
    if ((tid & 63) == 0) { red[w] = sum; red[4 + w] = sumsq; }
    __syncthreads();
    if (tid == 0) {
        float s1 = red[0] + red[1] + red[2] + red[3];
        float s2 = red[4] + red[5] + red[6] + red[7];
        float mean = s1 * (1.f / 65536.f);
        float var  = s2 * (1.f / 65536.f) - mean * mean;
        stats[0] = mean; stats[1] = rsqrtf(var + GN_EPS);
    }
    __syncthreads();
    if (tid < 16) {
        const int ch = g * 16 + tid;
        const float sc = gs[ch] * stats[1];
        scA[b * 512 + ch] = sc;
        biA[b * 512 + ch] = gb[ch] - stats[0] * sc;
    }
}

// ---------------------------------------------------------------------------
// Fused GN-normalize + QKV GEMM.  A = x*sc+bi (fp32->bf16), B = wqkvT rows.
//   n in [0,1024): qk[m][n] = C + bias  (q-part additionally pre-scaled by
//                  ATT_SCALE so attn's softmax skips the 8 muls per iter)
//   n in [1024,1536): C+bias -> transposed into vT[b][ch][tok] via LDS
// 128x128 tile, BK=32, 4 waves. grid (M/128, 12), block 256.
// ---------------------------------------------------------------------------
__global__ __launch_bounds__(256)
void gemm_qkv(const float* __restrict__ x, const float* __restrict__ scA,
              const float* __restrict__ biA, const __bf16* __restrict__ Bt,
              const float* __restrict__ bias,
              __bf16* __restrict__ qk, __bf16* __restrict__ vT)
{
    const int bm = blockIdx.x * 128, bn = blockIdx.y * 128;
    const int tid = threadIdx.x;
    const int w = tid >> 6, lane = tid & 63, quad = lane >> 4, l15 = lane & 15;
    const int wm = (w >> 1) * 64, wn = (w & 1) * 64;
    const int brow = bm >> 12;                  // batch of this m-tile

    __shared__ __bf16 sAB[2][128][40];          // As = sAB[0], Bs = sAB[1]

    f32x4 acc[4][4];
#pragma unroll
    for (int i = 0; i < 4; ++i)
#pragma unroll
        for (int j = 0; j < 4; ++j) acc[i][j] = (f32x4){0.f, 0.f, 0.f, 0.f};

    const int sr = tid >> 2, scol = (tid & 3) * 8;
    for (int k0 = 0; k0 < 512; k0 += 32) {
        __syncthreads();
        {   // A: load fp32 x, apply GN scale/bias, stage bf16
            const float* scp = scA + brow * 512 + k0 + scol;
            const float* bip = biA + brow * 512 + k0 + scol;
            f32x4 s0v = *(const f32x4*)&scp[0], s1v = *(const f32x4*)&scp[4];
            f32x4 b0v = *(const f32x4*)&bip[0], b1v = *(const f32x4*)&bip[4];
            f32x4 xa0 = *(const f32x4*)&x[(size_t)(bm + sr) * 512 + k0 + scol];
            f32x4 xa1 = *(const f32x4*)&x[(size_t)(bm + sr) * 512 + k0 + scol + 4];
            f32x4 xb0 = *(const f32x4*)&x[(size_t)(bm + sr + 64) * 512 + k0 + scol];
            f32x4 xb1 = *(const f32x4*)&x[(size_t)(bm + sr + 64) * 512 + k0 + scol + 4];
            bfx8 ha, hb;
#pragma unroll
            for (int j = 0; j < 4; ++j) {
                ha[j]     = (__bf16)(xa0[j] * s0v[j] + b0v[j]);
                ha[4 + j] = (__bf16)(xa1[j] * s1v[j] + b1v[j]);
                hb[j]     = (__bf16)(xb0[j] * s0v[j] + b0v[j]);
                hb[4 + j] = (__bf16)(xb1[j] * s1v[j] + b1v[j]);
            }
            *(bfx8*)&sAB[0][sr][scol]      = ha;
            *(bfx8*)&sAB[0][sr + 64][scol] = hb;
        }
        *(bfx8*)&sAB[1][sr][scol]      = *(const bfx8*)&Bt[(size_t)(bn + sr) * 512 + k0 + scol];
        *(bfx8*)&sAB[1][sr + 64][scol] = *(const bfx8*)&Bt[(size_t)(bn + sr + 64) * 512 + k0 + scol];
        __syncthreads();
        bfx8 af[4], bfr[4];
#pragma unroll
        for (int mi = 0; mi < 4; ++mi) af[mi]  = *(const bfx8*)&sAB[0][wm + mi * 16 + l15][quad * 8];
#pragma unroll
        for (int ni = 0; ni < 4; ++ni) bfr[ni] = *(const bfx8*)&sAB[1][wn + ni * 16 + l15][quad * 8];
#pragma unroll
        for (int mi = 0; mi < 4; ++mi)
#pragma unroll
            for (int ni = 0; ni < 4; ++ni)
                acc[mi][ni] = MFMA16(af[mi], bfr[ni], acc[mi][ni]);
    }

    if (blockIdx.y < 8) {
        // q/k epilogue: direct store, D row = quad*4+reg, col = l15.
        // q columns (bn < 512) carry ATT_SCALE so attn's softmax needn't.
        const float scale = (blockIdx.y < 4) ? ATT_SCALE : 1.0f;
#pragma unroll
        for (int ni = 0; ni < 4; ++ni) {
            const int col = bn + wn + ni * 16 + l15;
            const float bv = bias[col];
#pragma unroll
            for (int mi = 0; mi < 4; ++mi)
#pragma unroll
                for (int rr = 0; rr < 4; ++rr) {
                    const int row = bm + wm + mi * 16 + quad * 4 + rr;
                    qk[(size_t)row * 1024 + col] = (__bf16)((acc[mi][ni][rr] + bv) * scale);
                }
        }
    } else {
        // v epilogue: transpose 128x128 tile into vT[b][ch][tok] via LDS
        const int vch0 = bn - 1024;
        const int tokbase = bm & 4095;
        __bf16* tb = &sAB[0][0][0];             // reuse As+Bs: [64][136] bf16
        __syncthreads();                         // all waves done reading frags
#pragma unroll
        for (int chunk = 0; chunk < 2; ++chunk) {
            if ((w & 1) == chunk) {
#pragma unroll
                for (int ni = 0; ni < 4; ++ni) {
                    const int chc = ni * 16 + l15;               // 0..63 in chunk
                    const float bv = bias[bn + chunk * 64 + chc];
#pragma unroll
                    for (int mi = 0; mi < 4; ++mi)
#pragma unroll
                        for (int rr = 0; rr < 4; ++rr) {
                            const int tok = wm + mi * 16 + quad * 4 + rr;
                            tb[chc * 136 + tok] = (__bf16)(acc[mi][ni][rr] + bv);
                        }
                }
            }
            __syncthreads();
            {   // cooperative coalesced store of the 64ch x 128tok chunk
                const int chn = tid >> 2, t0 = (tid & 3) * 32;
                const size_t gb0 =
                    ((size_t)(brow * 512 + vch0 + chunk * 64 + chn)) * 4096 + tokbase;
#pragma unroll
                for (int u = 0; u < 4; ++u)
                    *(bfx8*)&vT[gb0 + t0 + u * 8] = *(const bfx8*)&tb[chn * 136 + t0 + u * 8];
            }
            __syncthreads();
        }
    }
}

// ---------------------------------------------------------------------------
// Flash attention + fused output projection + residual (fp32 out), v6.
// = v4 (best measured: single-barrier DMA pipeline, wave-local PV, zero
//   intra-iteration cross-wave sync) + T5 setprio around both MFMA clusters
//   + Q pre-scaled by ATT_SCALE upstream (softmax critical path shortened).
// Rationale (r2 post-mortem): kernel is serialization-bound, not LDS-port-
//   bound (48 B/cyc of 128); any intra-iter block barrier costs ~70us.
//   Register budget is exactly at the 256/wave cliff (VGPR 128 + AGPR 128,
//   2 waves/SIMD) -- all changes here add ZERO registers.
// grid (NTOK/128, B), block 512 (8 waves).
// ---------------------------------------------------------------------------
__global__ __launch_bounds__(512, 2)
void attn_fused(const __bf16* __restrict__ qk, const __bf16* __restrict__ vT,
                const __bf16* __restrict__ woT, const float* __restrict__ bo,
                const float* __restrict__ x, float* __restrict__ out)
{
    const int bb = blockIdx.y;
    const int q0 = blockIdx.x * 128;
    const int tid = threadIdx.x;
    const int w = tid >> 6, lane = tid & 63, quad = lane >> 4, l15 = lane & 15;

    __shared__ __attribute__((aligned(16))) unsigned char smem[141312];
    __bf16 (*Ks)[32][512]      = (__bf16(*)[32][512])smem;                // 2 x 32 KiB
    __bf16 (*Vs)[32][4][16][8] = (__bf16(*)[32][4][16][8])(smem + 65536); // 2 x 32 KiB
    __bf16 (*Ph)[40]           = (__bf16(*)[40])(smem + 131072);          // 128x40 (wave-private strips)
    __bf16 (*Obuf)[520]        = (__bf16(*)[520])smem;                    // 64x520 epilogue overlay

    // Q rows for this wave's S^T columns, full K=512, in registers (64 VGPRs)
    bfx8 qf[16];
    {
        const __bf16* qptr = qk + ((size_t)(bb * NTOK + q0 + w * 16 + l15)) * 1024;
#pragma unroll
        for (int kk = 0; kk < 16; ++kk)
            qf[kk] = *(const bfx8*)&qptr[kk * 32 + quad * 8];
    }

    // O^T accumulator: lane's col = its OWN q-row (w*16+l15);
    // oacc[ct][r] = channel ct*16 + quad*4 + r.  128 VGPRs.
    f32x4 oacc[32];
#pragma unroll
    for (int i = 0; i < 32; ++i) oacc[i] = (f32x4){0.f, 0.f, 0.f, 0.f};
    float mcur = -1e30f, lcur = 0.f;

    // ---- tile-0 DMA: wave w stages K rows [w*4,w*4+4) and V ch-groups [w*4,w*4+4)
#pragma unroll
    for (int u = 0; u < 4; ++u) {
        const int r = w * 4 + u;
        gload16(qk + ((size_t)(bb * NTOK + r)) * 1024 + 512 + ((lane ^ (r & 7)) * 8),
                &Ks[0][r][0]);
    }
#pragma unroll
    for (int u = 0; u < 4; ++u) {
        const int g = w * 4 + u;
        gload16(vT + ((size_t)(bb * 512 + g * 16 + (lane & 15))) * 4096 + (lane >> 4) * 8,
                &Vs[0][g][0][0][0]);
    }

    const int NT = NTOK / 32;   // 128
    int buf = 0;
    for (int kt = 0; kt < NT; ++kt) {
        // THE one barrier: this wave's DMA drained (vmcnt 0), all waves synced.
        // After it: tile kt fully in LDS, buf^1 free to overwrite.
        __syncthreads();

        if (kt + 1 < NT) {
            const int kv1 = (kt + 1) * 32;
            const int nb = buf ^ 1;
#pragma unroll
            for (int u = 0; u < 4; ++u) {
                const int r = w * 4 + u;
                gload16(qk + ((size_t)(bb * NTOK + kv1 + r)) * 1024 + 512 + ((lane ^ (r & 7)) * 8),
                        &Ks[nb][r][0]);
            }
#pragma unroll
            for (int u = 0; u < 4; ++u) {
                const int g = w * 4 + u;
                gload16(vT + ((size_t)(bb * 512 + g * 16 + (lane & 15))) * 4096 + kv1 + (lane >> 4) * 8,
                        &Vs[nb][g][0][0][0]);
            }
        }

        // S^T: s0 -> j = quad*4+i, s1 -> j = 16+quad*4+i, column m = l15.
        // K read swizzled: phys chunk = (kk*4+quad) ^ (l15&7)
        f32x4 s0 = (f32x4){0.f, 0.f, 0.f, 0.f}, s1 = (f32x4){0.f, 0.f, 0.f, 0.f};
        __builtin_amdgcn_s_setprio(1);
#pragma unroll
        for (int kk = 0; kk < 16; ++kk) {
            const int pc = (((kk * 4 + quad) ^ (l15 & 7)) * 8);
            bfx8 kb0 = *(const bfx8*)&Ks[buf][l15][pc];
            bfx8 kb1 = *(const bfx8*)&Ks[buf][16 + l15][pc];
            s0 = MFMA16(kb0, qf[kk], s0);
            s1 = MFMA16(kb1, qf[kk], s1);
        }
        __builtin_amdgcn_s_setprio(0);

        // wave-local online softmax for row m = l15 (replicated across quads);
        // Q carries ATT_SCALE already -- s0/s1 are final logits.
        float mx = -1e30f;
#pragma unroll
        for (int i = 0; i < 4; ++i)
            mx = fmaxf(mx, fmaxf(s0[i], s1[i]));
        mx = fmaxf(mx, __shfl_xor(mx, 16));
        mx = fmaxf(mx, __shfl_xor(mx, 32));
        const float mnew = fmaxf(mcur, mx);
        const float al = __expf(mcur - mnew);
        float ps = 0.f;
        bfx4 pl0, pl1;
#pragma unroll
        for (int i = 0; i < 4; ++i) { float p = __expf(s0[i] - mnew); ps += p; pl0[i] = (__bf16)p; }
#pragma unroll
        for (int i = 0; i < 4; ++i) { float p = __expf(s1[i] - mnew); ps += p; pl1[i] = (__bf16)p; }
        ps += __shfl_xor(ps, 16);
        ps += __shfl_xor(ps, 32);
        lcur = lcur * al + ps;
        mcur = mnew;

        // wave-private P repack through LDS (intra-wave only: lgkm order, no barrier)
        *(bfx4*)&Ph[w * 16 + l15][quad * 4]      = pl0;
        *(bfx4*)&Ph[w * 16 + l15][16 + quad * 4] = pl1;

        // per-lane rescale of the lane's own row (no abuf, no cross-lane)
        if (__any(al != 1.0f)) {
#pragma unroll
            for (int ct = 0; ct < 32; ++ct)
#pragma unroll
                for (int r = 0; r < 4; ++r) oacc[ct][r] *= al;
        }

        asm volatile("s_waitcnt lgkmcnt(0)" ::: "memory");  // Ph writes visible wave-wide
        bfx8 pa = *(const bfx8*)&Ph[w * 16 + l15][quad * 8];

        // O^T += mfma(a = V^T chunk, b = P): 32 contiguous 1KB LDS blocks
        __builtin_amdgcn_s_setprio(1);
#pragma unroll
        for (int ct = 0; ct < 32; ++ct) {
            bfx8 vb = *(const bfx8*)&Vs[buf][ct][quad][l15][0];
            oacc[ct] = MFMA16(vb, pa, oacc[ct]);
        }
        __builtin_amdgcn_s_setprio(0);
        buf ^= 1;
    }

    // ---- epilogue: normalize + projection + bias + residual, 2 half-passes --
#pragma unroll
    for (int h = 0; h < 2; ++h) {
        __syncthreads();   // K/V reads done (h=0) / prev half's Obuf reads done
        if ((w >> 2) == h) {
            const float linv = 1.f / lcur;                   // lane-local l
#pragma unroll
            for (int ct = 0; ct < 32; ++ct) {
                bfx4 ov;
#pragma unroll
                for (int r = 0; r < 4; ++r) ov[r] = (__bf16)(oacc[ct][r] * linv);
                *(bfx4*)&Obuf[(w & 3) * 16 + l15][ct * 16 + quad * 4] = ov;
            }
        }
        __syncthreads();

        // project rows [h*64, h*64+64): wave strip rows (w&3)*16, cols (w>>2)*256
        const int rs  = (w & 3) * 16;
        const int nt0 = (w >> 2) * 16;
        bfx8 af2[16];
#pragma unroll
        for (int k0 = 0; k0 < 16; ++k0)
            af2[k0] = *(const bfx8*)&Obuf[rs + l15][k0 * 32 + quad * 8];
#pragma unroll 4
        for (int nt = 0; nt < 16; ++nt) {
            f32x4 a2 = (f32x4){0.f, 0.f, 0.f, 0.f};
#pragma unroll
            for (int k0 = 0; k0 < 16; ++k0) {
                bfx8 wb = *(const bfx8*)&woT[(size_t)((nt0 + nt) * 16 + l15) * 512 + k0 * 32 + quad * 8];
                a2 = MFMA16(af2[k0], wb, a2);
            }
            const int col = (nt0 + nt) * 16 + l15;
            const float bv = bo[col];
#pragma unroll
            for (int rr = 0; rr < 4; ++rr) {
                const size_t idx =
                    ((size_t)(bb * NTOK + q0 + h * 64 + rs + quad * 4 + rr)) * 512 + col;
                out[idx] = a2[rr] + bv + x[idx];
            }
        }
    }
}

// ---------------------------------------------------------------------------
extern "C" void kernel_launch(void* const* d_in, const int* in_sizes, int n_in,
                              void* d_out, int out_size, void* d_ws, size_t ws_size,
                              hipStream_t stream)
{
    const float* x  = (const float*)d_in[0];
    const float* gs = (const float*)d_in[1];
    const float* gb = (const float*)d_in[2];
    const float* wq = (const float*)d_in[3];
    const float* bq = (const float*)d_in[4];
    const float* wk = (const float*)d_in[5];
    const float* bk = (const float*)d_in[6];
    const float* wv = (const float*)d_in[7];
    const float* bv = (const float*)d_in[8];
    const float* wo = (const float*)d_in[9];
    const float* bo = (const float*)d_in[10];
    float* out = (float*)d_out;

    // workspace layout -- total 102,799,360 B (~98 MiB)
    char* ws = (char*)d_ws;
    __bf16* qk    = (__bf16*)(ws);                    //  67,108,864 B [32768][1024]
    __bf16* vT    = (__bf16*)(ws + 67108864);         //  33,554,432 B [8][512][4096]
    __bf16* wqkvT = (__bf16*)(ws + 100663296);        //   1,572,864 B [1536][512]
    __bf16* woT   = (__bf16*)(ws + 102236160);        //     524,288 B [512][512]
    float*  bqkv  = (float* )(ws + 102760448);        //       6,144 B [1536]
    float*  scA   = (float* )(ws + 102766592);        //      16,384 B [8][512]
    float*  biA   = (float* )(ws + 102782976);        //      16,384 B [8][512]

    prep_weights<<<dim3(16, 16, 4), 256, 0, stream>>>(wq, wk, wv, wo, bq, bk, bv,
                                                      wqkvT, woT, bqkv);
    gn_stats<<<dim3(32, BATCH), 256, 0, stream>>>(x, gs, gb, scA, biA);
    gemm_qkv<<<dim3(256, 12), 256, 0, stream>>>(x, scA, biA, wqkvT, bqkv, qk, vT);
    attn_fused<<<dim3(NTOK / 128, BATCH), 512, 0, stream>>>(qk, vT, woT, bo, x, out);
}

// Round 4
// 711.604 us; speedup vs baseline: 1.1976x; 1.0398x over previous
//
#include <hip/hip_runtime.h>

typedef __bf16 bfx8 __attribute__((ext_vector_type(8)));
typedef __bf16 bfx4 __attribute__((ext_vector_type(4)));
typedef float  f32x4 __attribute__((ext_vector_type(4)));

#define MFMA16(a,b,c) __builtin_amdgcn_mfma_f32_16x16x32_bf16((a),(b),(c),0,0,0)

static constexpr int BATCH = 8;
static constexpr int NTOK  = 4096;   // 64*64 spatial
static constexpr int CH    = 512;
static constexpr float GN_EPS = 1e-5f;
static constexpr float ATT_SCALE = 0.044194173824159216f; // 512^-0.5

// direct HBM->LDS, 16B per lane; LDS dest = wave-uniform base + lane*16
__device__ __forceinline__ void gload16(const void* g, void* l)
{
    __builtin_amdgcn_global_load_lds(
        (const __attribute__((address_space(1))) unsigned int*)g,
        (__attribute__((address_space(3))) unsigned int*)l, 16, 0, 0);
}

// ---------------------------------------------------------------------------
// prep: fp32 weights -> bf16 transposed (wT[n][c] = w[c][n]); concat fp32 biases.
// grid (16,16,4) z: 0=wq 1=wk 2=wv 3=wo. block 256.
// ---------------------------------------------------------------------------
__global__ __launch_bounds__(256)
void prep_weights(const float* __restrict__ wq, const float* __restrict__ wk,
                  const float* __restrict__ wv, const float* __restrict__ wo,
                  const float* __restrict__ bq, const float* __restrict__ bk,
                  const float* __restrict__ bv,
                  __bf16* __restrict__ wqkvT, __bf16* __restrict__ woT,
                  float* __restrict__ bqkv)
{
    __shared__ __bf16 t[32][36];
    const int z  = blockIdx.z;
    const float* src = (z == 0) ? wq : (z == 1) ? wk : (z == 2) ? wv : wo;
    const int c0 = blockIdx.x * 32, n0 = blockIdx.y * 32;
    const int tid = threadIdx.x;
    const int r = tid >> 3, c4 = (tid & 7) * 4;

    f32x4 in = *(const f32x4*)&src[(size_t)(c0 + r) * 512 + n0 + c4];
    bfx4 tv;
#pragma unroll
    for (int i = 0; i < 4; ++i) tv[i] = (__bf16)in[i];
    *(bfx4*)&t[r][c4] = tv;
    __syncthreads();
    bfx4 o;
#pragma unroll
    for (int i = 0; i < 4; ++i) o[i] = t[c4 + i][r];
    if (z < 3)
        *(bfx4*)&wqkvT[((size_t)(z * 512 + n0 + r)) * 512 + c0 + c4] = o;
    else
        *(bfx4*)&woT[((size_t)(n0 + r)) * 512 + c0 + c4] = o;

    if (z < 3 && blockIdx.x == 0 && blockIdx.y == 0) {
        const float* bs = (z == 0) ? bq : (z == 1) ? bk : bv;
        bqkv[z * 512 + tid]       = bs[tid];
        bqkv[z * 512 + tid + 256] = bs[tid + 256];
    }
}

// ---------------------------------------------------------------------------
// GroupNorm statistics: one block per (g, b). Writes per-channel fused
// scale/bias:  h[ch] = x[ch]*scA[b][ch] + biA[b][ch].  grid (32, 8), block 256.
// ---------------------------------------------------------------------------
__global__ __launch_bounds__(256)
void gn_stats(const float* __restrict__ x, const float* __restrict__ gs,
              const float* __restrict__ gb,
              float* __restrict__ scA, float* __restrict__ biA)
{
    const int g = blockIdx.x, b = blockIdx.y;
    const int tid = threadIdx.x;
    const int half = tid & 1;
    const size_t base = (size_t)b * NTOK * CH + g * 16 + half * 8;

    float sum = 0.f, sumsq = 0.f;
    for (int i = tid; i < 2 * NTOK; i += 256) {
        const int s = i >> 1;
        f32x4 v0 = *(const f32x4*)&x[base + (size_t)s * CH];
        f32x4 v1 = *(const f32x4*)&x[base + (size_t)s * CH + 4];
#pragma unroll
        for (int j = 0; j < 4; ++j) {
            sum += v0[j] + v1[j];
            sumsq += v0[j] * v0[j] + v1[j] * v1[j];
        }
    }
#pragma unroll
    for (int o = 32; o; o >>= 1) { sum += __shfl_down(sum, o); sumsq += __shfl_down(sumsq, o); }
    __shared__ float red[8];
    __shared__ float stats[2];
    const int w = tid >> 6;
    if ((tid & 63) == 0) { red[w] = sum; red[4 + w] = sumsq; }
    __syncthreads();
    if (tid == 0) {
        float s1 = red[0] + red[1] + red[2] + red[3];
        float s2 = red[4] + red[5] + red[6] + red[7];
        float mean = s1 * (1.f / 65536.f);
        float var  = s2 * (1.f / 65536.f) - mean * mean;
        stats[0] = mean; stats[1] = rsqrtf(var + GN_EPS);
    }
    __syncthreads();
    if (tid < 16) {
        const int ch = g * 16 + tid;
        const float sc = gs[ch] * stats[1];
        scA[b * 512 + ch] = sc;
        biA[b * 512 + ch] = gb[ch] - stats[0] * sc;
    }
}

// ---------------------------------------------------------------------------
// Fused GN-normalize + QKV GEMM, v2 pipeline.
//   A = x*sc+bi (fp32->bf16, VALU-staged, x prefetched to regs 1 step ahead)
//   B = wqkvT rows, staged via global_load_lds into DOUBLE-BUFFERED
//       XOR-swizzled Bs (issued 1 K-step ahead; second barrier is raw
//       lgkmcnt+s_barrier so the DMA stays in flight across it).
//   Bs swizzle: phys col-chunk = logical ^ (row&3); source pre-swizzled,
//   frag read applies the same XOR (both-sides rule).
//   n in [0,1024): qk[m][n] = C + bias (q cols carry ATT_SCALE)
//   n in [1024,1536): C+bias -> transposed into vT[b][ch][tok] via LDS
// 128x128 tile, BK=32, 4 waves. grid (M/128, 12), block 256.
// ---------------------------------------------------------------------------
__global__ __launch_bounds__(256)
void gemm_qkv(const float* __restrict__ x, const float* __restrict__ scA,
              const float* __restrict__ biA, const __bf16* __restrict__ Bt,
              const float* __restrict__ bias,
              __bf16* __restrict__ qk, __bf16* __restrict__ vT)
{
    const int bm = blockIdx.x * 128, bn = blockIdx.y * 128;
    const int tid = threadIdx.x;
    const int w = tid >> 6, lane = tid & 63, quad = lane >> 4, l15 = lane & 15;
    const int wm = (w >> 1) * 64, wn = (w & 1) * 64;
    const int brow = bm >> 12;                  // batch of this m-tile

    // As[128][40] (10240B) + Bs[2][128][32] (16384B) = 26624B
    __shared__ __attribute__((aligned(16))) __bf16 smem_g[5120 + 2 * 128 * 32];
    __bf16 (*As)[40] = (__bf16(*)[40])smem_g;
    __bf16 (*Bs)[128][32] = (__bf16(*)[128][32])(smem_g + 5120);

    f32x4 acc[4][4];
#pragma unroll
    for (int i = 0; i < 4; ++i)
#pragma unroll
        for (int j = 0; j < 4; ++j) acc[i][j] = (f32x4){0.f, 0.f, 0.f, 0.f};

    const int sr = tid >> 2, scol = (tid & 3) * 8;
    // B DMA lane mapping: row = w*32 + u*16 + (lane>>2), phys chunk = lane&3,
    // source chunk = (lane&3) ^ (row&3).
    const int brow_l = (lane >> 2);
    const int bcp    = lane & 3;

    // ---- prologue: issue B(k0=0) DMA; prefetch x(k0=0) into regs
#pragma unroll
    for (int u = 0; u < 2; ++u) {
        const int row = w * 32 + u * 16 + brow_l;
        gload16(Bt + (size_t)(bn + row) * 512 + ((bcp ^ (row & 3)) * 8),
                &Bs[0][w * 32 + u * 16][0]);
    }
    f32x4 xa0 = *(const f32x4*)&x[(size_t)(bm + sr) * 512 + scol];
    f32x4 xa1 = *(const f32x4*)&x[(size_t)(bm + sr) * 512 + scol + 4];
    f32x4 xb0 = *(const f32x4*)&x[(size_t)(bm + sr + 64) * 512 + scol];
    f32x4 xb1 = *(const f32x4*)&x[(size_t)(bm + sr + 64) * 512 + scol + 4];

    for (int k0 = 0; k0 < 512; k0 += 32) {
        const int cur = (k0 >> 5) & 1;
        __syncthreads();   // sync1: B[cur] DMA drained (vmcnt 0); As free
        {   // A: GN-transform prefetched x, stage bf16 into As
            const float* scp = scA + brow * 512 + k0 + scol;
            const float* bip = biA + brow * 512 + k0 + scol;
            f32x4 s0v = *(const f32x4*)&scp[0], s1v = *(const f32x4*)&scp[4];
            f32x4 b0v = *(const f32x4*)&bip[0], b1v = *(const f32x4*)&bip[4];
            bfx8 ha, hb;
#pragma unroll
            for (int j = 0; j < 4; ++j) {
                ha[j]     = (__bf16)(xa0[j] * s0v[j] + b0v[j]);
                ha[4 + j] = (__bf16)(xa1[j] * s1v[j] + b1v[j]);
                hb[j]     = (__bf16)(xb0[j] * s0v[j] + b0v[j]);
                hb[4 + j] = (__bf16)(xb1[j] * s1v[j] + b1v[j]);
            }
            *(bfx8*)&As[sr][scol]      = ha;
            *(bfx8*)&As[sr + 64][scol] = hb;
        }
        if (k0 + 32 < 512) {   // issue next B DMA + next x prefetch
            const int k1 = k0 + 32;
#pragma unroll
            for (int u = 0; u < 2; ++u) {
                const int row = w * 32 + u * 16 + brow_l;
                gload16(Bt + (size_t)(bn + row) * 512 + k1 + ((bcp ^ (row & 3)) * 8),
                        &Bs[cur ^ 1][w * 32 + u * 16][0]);
            }
            xa0 = *(const f32x4*)&x[(size_t)(bm + sr) * 512 + k1 + scol];
            xa1 = *(const f32x4*)&x[(size_t)(bm + sr) * 512 + k1 + scol + 4];
            xb0 = *(const f32x4*)&x[(size_t)(bm + sr + 64) * 512 + k1 + scol];
            xb1 = *(const f32x4*)&x[(size_t)(bm + sr + 64) * 512 + k1 + scol + 4];
        }
        // sync2: As writes visible; raw barrier (no vmcnt drain -> B/x stay in flight)
        asm volatile("s_waitcnt lgkmcnt(0)\n\ts_barrier" ::: "memory");

        bfx8 af[4], bfr[4];
#pragma unroll
        for (int mi = 0; mi < 4; ++mi) af[mi] = *(const bfx8*)&As[wm + mi * 16 + l15][quad * 8];
#pragma unroll
        for (int ni = 0; ni < 4; ++ni) {
            const int row = wn + ni * 16 + l15;
            bfr[ni] = *(const bfx8*)&Bs[cur][row][(quad ^ (row & 3)) * 8];
        }
#pragma unroll
        for (int mi = 0; mi < 4; ++mi)
#pragma unroll
            for (int ni = 0; ni < 4; ++ni)
                acc[mi][ni] = MFMA16(af[mi], bfr[ni], acc[mi][ni]);
    }

    if (blockIdx.y < 8) {
        // q/k epilogue: direct store, D row = quad*4+reg, col = l15.
        // q columns (bn < 512) carry ATT_SCALE so attn's softmax needn't.
        const float scale = (blockIdx.y < 4) ? ATT_SCALE : 1.0f;
#pragma unroll
        for (int ni = 0; ni < 4; ++ni) {
            const int col = bn + wn + ni * 16 + l15;
            const float bv = bias[col];
#pragma unroll
            for (int mi = 0; mi < 4; ++mi)
#pragma unroll
                for (int rr = 0; rr < 4; ++rr) {
                    const int row = bm + wm + mi * 16 + quad * 4 + rr;
                    qk[(size_t)row * 1024 + col] = (__bf16)((acc[mi][ni][rr] + bv) * scale);
                }
        }
    } else {
        // v epilogue: transpose 128x128 tile into vT[b][ch][tok] via LDS
        const int vch0 = bn - 1024;
        const int tokbase = bm & 4095;
        __bf16* tb = smem_g;                    // scratch [64][136] = 17408B <= 26624B
        __syncthreads();                         // all waves done reading frags
#pragma unroll
        for (int chunk = 0; chunk < 2; ++chunk) {
            if ((w & 1) == chunk) {
#pragma unroll
                for (int ni = 0; ni < 4; ++ni) {
                    const int chc = ni * 16 + l15;               // 0..63 in chunk
                    const float bv = bias[bn + chunk * 64 + chc];
#pragma unroll
                    for (int mi = 0; mi < 4; ++mi)
#pragma unroll
                        for (int rr = 0; rr < 4; ++rr) {
                            const int tok = wm + mi * 16 + quad * 4 + rr;
                            tb[chc * 136 + tok] = (__bf16)(acc[mi][ni][rr] + bv);
                        }
                }
            }
            __syncthreads();
            {   // cooperative coalesced store of the 64ch x 128tok chunk
                const int chn = tid >> 2, t0 = (tid & 3) * 32;
                const size_t gb0 =
                    ((size_t)(brow * 512 + vch0 + chunk * 64 + chn)) * 4096 + tokbase;
#pragma unroll
                for (int u = 0; u < 4; ++u)
                    *(bfx8*)&vT[gb0 + t0 + u * 8] = *(const bfx8*)&tb[chn * 136 + t0 + u * 8];
            }
            __syncthreads();
        }
    }
}

// ---------------------------------------------------------------------------
// Flash attention + fused output projection + residual (fp32 out), v7.
// = v6 (single-barrier DMA pipeline, wave-local PV, setprio, prescaled Q)
//   + T13 deferred-max softmax with SPECULATIVE exp:
//     fast path: P = exp(s - mcur) issued immediately (no wait on the
//     cross-quad max reduce); mx reduce runs in parallel; slow path
//     (mx > mcur+8, ~1-2 iters total on N(0,1) logits) rescales + recomputes.
//     Steady-state critical path loses: 2 shfl latencies, fmax/mnew chain,
//     the alpha exp, and the 128-mul rescale (fired ~78/128 iters before).
//   lcur accumulation moved after PV (off critical path).
// grid (NTOK/128, B), block 512 (8 waves).  Regs: qf 64 + oacc 128 (<=256).
// ---------------------------------------------------------------------------
__global__ __launch_bounds__(512, 2)
void attn_fused(const __bf16* __restrict__ qk, const __bf16* __restrict__ vT,
                const __bf16* __restrict__ woT, const float* __restrict__ bo,
                const float* __restrict__ x, float* __restrict__ out)
{
    const int bb = blockIdx.y;
    const int q0 = blockIdx.x * 128;
    const int tid = threadIdx.x;
    const int w = tid >> 6, lane = tid & 63, quad = lane >> 4, l15 = lane & 15;

    __shared__ __attribute__((aligned(16))) unsigned char smem[141312];
    __bf16 (*Ks)[32][512]      = (__bf16(*)[32][512])smem;                // 2 x 32 KiB
    __bf16 (*Vs)[32][4][16][8] = (__bf16(*)[32][4][16][8])(smem + 65536); // 2 x 32 KiB
    __bf16 (*Ph)[40]           = (__bf16(*)[40])(smem + 131072);          // 128x40 (wave-private strips)
    __bf16 (*Obuf)[520]        = (__bf16(*)[520])smem;                    // 64x520 epilogue overlay

    // Q rows for this wave's S^T columns, full K=512, in registers (64 VGPRs)
    bfx8 qf[16];
    {
        const __bf16* qptr = qk + ((size_t)(bb * NTOK + q0 + w * 16 + l15)) * 1024;
#pragma unroll
        for (int kk = 0; kk < 16; ++kk)
            qf[kk] = *(const bfx8*)&qptr[kk * 32 + quad * 8];
    }

    // O^T accumulator: lane's col = its OWN q-row (w*16+l15);
    // oacc[ct][r] = channel ct*16 + quad*4 + r.  128 VGPRs.
    f32x4 oacc[32];
#pragma unroll
    for (int i = 0; i < 32; ++i) oacc[i] = (f32x4){0.f, 0.f, 0.f, 0.f};
    float mcur = -1e30f, lcur = 0.f;

    // ---- tile-0 DMA: wave w stages K rows [w*4,w*4+4) and V ch-groups [w*4,w*4+4)
#pragma unroll
    for (int u = 0; u < 4; ++u) {
        const int r = w * 4 + u;
        gload16(qk + ((size_t)(bb * NTOK + r)) * 1024 + 512 + ((lane ^ (r & 7)) * 8),
                &Ks[0][r][0]);
    }
#pragma unroll
    for (int u = 0; u < 4; ++u) {
        const int g = w * 4 + u;
        gload16(vT + ((size_t)(bb * 512 + g * 16 + (lane & 15))) * 4096 + (lane >> 4) * 8,
                &Vs[0][g][0][0][0]);
    }

    const int NT = NTOK / 32;   // 128
    int buf = 0;
    for (int kt = 0; kt < NT; ++kt) {
        // THE one barrier: this wave's DMA drained (vmcnt 0), all waves synced.
        __syncthreads();

        if (kt + 1 < NT) {
            const int kv1 = (kt + 1) * 32;
            const int nb = buf ^ 1;
#pragma unroll
            for (int u = 0; u < 4; ++u) {
                const int r = w * 4 + u;
                gload16(qk + ((size_t)(bb * NTOK + kv1 + r)) * 1024 + 512 + ((lane ^ (r & 7)) * 8),
                        &Ks[nb][r][0]);
            }
#pragma unroll
            for (int u = 0; u < 4; ++u) {
                const int g = w * 4 + u;
                gload16(vT + ((size_t)(bb * 512 + g * 16 + (lane & 15))) * 4096 + kv1 + (lane >> 4) * 8,
                        &Vs[nb][g][0][0][0]);
            }
        }

        // S^T: s0 -> j = quad*4+i, s1 -> j = 16+quad*4+i, column m = l15.
        // K read swizzled: phys chunk = (kk*4+quad) ^ (l15&7)
        f32x4 s0 = (f32x4){0.f, 0.f, 0.f, 0.f}, s1 = (f32x4){0.f, 0.f, 0.f, 0.f};
        __builtin_amdgcn_s_setprio(1);
#pragma unroll
        for (int kk = 0; kk < 16; ++kk) {
            const int pc = (((kk * 4 + quad) ^ (l15 & 7)) * 8);
            bfx8 kb0 = *(const bfx8*)&Ks[buf][l15][pc];
            bfx8 kb1 = *(const bfx8*)&Ks[buf][16 + l15][pc];
            s0 = MFMA16(kb0, qf[kk], s0);
            s1 = MFMA16(kb1, qf[kk], s1);
        }
        __builtin_amdgcn_s_setprio(0);

        // --- deferred-max softmax (T13), speculative fast path ---
        float mx = -1e30f;
#pragma unroll
        for (int i = 0; i < 4; ++i) mx = fmaxf(mx, fmaxf(s0[i], s1[i]));
        float ps = 0.f;
        bfx4 pl0, pl1;
#pragma unroll
        for (int i = 0; i < 4; ++i) { float p = __expf(s0[i] - mcur); ps += p; pl0[i] = (__bf16)p; }
#pragma unroll
        for (int i = 0; i < 4; ++i) { float p = __expf(s1[i] - mcur); ps += p; pl1[i] = (__bf16)p; }
        mx = fmaxf(mx, __shfl_xor(mx, 16));
        mx = fmaxf(mx, __shfl_xor(mx, 32));
        if (__builtin_expect(__any(mx > mcur + 8.f), 0)) {
            // slow path (~1-2 iters): raise running max, rescale, recompute P
            const float mnew = fmaxf(mcur, mx);
            const float al = __expf(mcur - mnew);
            lcur *= al;
            ps = 0.f;
#pragma unroll
            for (int i = 0; i < 4; ++i) { float p = __expf(s0[i] - mnew); ps += p; pl0[i] = (__bf16)p; }
#pragma unroll
            for (int i = 0; i < 4; ++i) { float p = __expf(s1[i] - mnew); ps += p; pl1[i] = (__bf16)p; }
            mcur = mnew;
#pragma unroll
            for (int ct = 0; ct < 32; ++ct)
#pragma unroll
                for (int r = 0; r < 4; ++r) oacc[ct][r] *= al;
        }

        // wave-private P repack through LDS (intra-wave only: lgkm order, no barrier)
        *(bfx4*)&Ph[w * 16 + l15][quad * 4]      = pl0;
        *(bfx4*)&Ph[w * 16 + l15][16 + quad * 4] = pl1;

        asm volatile("s_waitcnt lgkmcnt(0)" ::: "memory");  // Ph writes visible wave-wide
        bfx8 pa = *(const bfx8*)&Ph[w * 16 + l15][quad * 8];

        // O^T += mfma(a = V^T chunk, b = P): 32 contiguous 1KB LDS blocks
        __builtin_amdgcn_s_setprio(1);
#pragma unroll
        for (int ct = 0; ct < 32; ++ct) {
            bfx8 vb = *(const bfx8*)&Vs[buf][ct][quad][l15][0];
            oacc[ct] = MFMA16(vb, pa, oacc[ct]);
        }
        __builtin_amdgcn_s_setprio(0);

        // l accumulation off the critical path (after PV issue)
        ps += __shfl_xor(ps, 16);
        ps += __shfl_xor(ps, 32);
        lcur += ps;
        buf ^= 1;
    }

    // ---- epilogue: normalize + projection + bias + residual, 2 half-passes --
#pragma unroll
    for (int h = 0; h < 2; ++h) {
        __syncthreads();   // K/V reads done (h=0) / prev half's Obuf reads done
        if ((w >> 2) == h) {
            const float linv = 1.f / lcur;                   // lane-local l
#pragma unroll
            for (int ct = 0; ct < 32; ++ct) {
                bfx4 ov;
#pragma unroll
                for (int r = 0; r < 4; ++r) ov[r] = (__bf16)(oacc[ct][r] * linv);
                *(bfx4*)&Obuf[(w & 3) * 16 + l15][ct * 16 + quad * 4] = ov;
            }
        }
        __syncthreads();

        // project rows [h*64, h*64+64): wave strip rows (w&3)*16, cols (w>>2)*256
        const int rs  = (w & 3) * 16;
        const int nt0 = (w >> 2) * 16;
        bfx8 af2[16];
#pragma unroll
        for (int k0 = 0; k0 < 16; ++k0)
            af2[k0] = *(const bfx8*)&Obuf[rs + l15][k0 * 32 + quad * 8];
#pragma unroll 4
        for (int nt = 0; nt < 16; ++nt) {
            f32x4 a2 = (f32x4){0.f, 0.f, 0.f, 0.f};
#pragma unroll
            for (int k0 = 0; k0 < 16; ++k0) {
                bfx8 wb = *(const bfx8*)&woT[(size_t)((nt0 + nt) * 16 + l15) * 512 + k0 * 32 + quad * 8];
                a2 = MFMA16(af2[k0], wb, a2);
            }
            const int col = (nt0 + nt) * 16 + l15;
            const float bv = bo[col];
#pragma unroll
            for (int rr = 0; rr < 4; ++rr) {
                const size_t idx =
                    ((size_t)(bb * NTOK + q0 + h * 64 + rs + quad * 4 + rr)) * 512 + col;
                out[idx] = a2[rr] + bv + x[idx];
            }
        }
    }
}

// ---------------------------------------------------------------------------
extern "C" void kernel_launch(void* const* d_in, const int* in_sizes, int n_in,
                              void* d_out, int out_size, void* d_ws, size_t ws_size,
                              hipStream_t stream)
{
    const float* x  = (const float*)d_in[0];
    const float* gs = (const float*)d_in[1];
    const float* gb = (const float*)d_in[2];
    const float* wq = (const float*)d_in[3];
    const float* bq = (const float*)d_in[4];
    const float* wk = (const float*)d_in[5];
    const float* bk = (const float*)d_in[6];
    const float* wv = (const float*)d_in[7];
    const float* bv = (const float*)d_in[8];
    const float* wo = (const float*)d_in[9];
    const float* bo = (const float*)d_in[10];
    float* out = (float*)d_out;

    // workspace layout -- total 102,799,360 B (~98 MiB)
    char* ws = (char*)d_ws;
    __bf16* qk    = (__bf16*)(ws);                    //  67,108,864 B [32768][1024]
    __bf16* vT    = (__bf16*)(ws + 67108864);         //  33,554,432 B [8][512][4096]
    __bf16* wqkvT = (__bf16*)(ws + 100663296);        //   1,572,864 B [1536][512]
    __bf16* woT   = (__bf16*)(ws + 102236160);        //     524,288 B [512][512]
    float*  bqkv  = (float* )(ws + 102760448);        //       6,144 B [1536]
    float*  scA   = (float* )(ws + 102766592);        //      16,384 B [8][512]
    float*  biA   = (float* )(ws + 102782976);        //      16,384 B [8][512]

    prep_weights<<<dim3(16, 16, 4), 256, 0, stream>>>(wq, wk, wv, wo, bq, bk, bv,
                                                      wqkvT, woT, bqkv);
    gn_stats<<<dim3(32, BATCH), 256, 0, stream>>>(x, gs, gb, scA, biA);
    gemm_qkv<<<dim3(256, 12), 256, 0, stream>>>(x, scA, biA, wqkvT, bqkv, qk, vT);
    attn_fused<<<dim3(NTOK / 128, BATCH), 512, 0, stream>>>(qk, vT, woT, bo, x, out);
}